// Round 7
// baseline (215.384 us; speedup 1.0000x reference)
//
#include <hip/hip_runtime.h>
#include <math.h>

// MutualInformationLoss on MI355X — round 7.
// Round-6: mi_mfma ~43 us (LDS-pipe-bound), but K2 (stride-2116B uncoalesced
// reads, 16x line amplification) + K3 (serial block) + launch gaps ate ~60 us.
// Fix: fuse reduce+final into mi_batch (4 blocks, coalesced fp64 streaming of
// the per-batch partial slab, marginals+MI in-block, fp32 atomicAdd to out).
// K1: zero 24 rows (3456 B) not 4096 B per image per chunk.

#define NBINS   23
#define NCELLS  529
#define NBATCH  4
#define NVOX    884736
#define PBLK    432               // blocks per batch: 432 * 2048 = 884736
#define RS      72                // image row stride in halves (144 B)
#define IMGB    (32 * RS * 2)     // 4608 B per image (32 rows)
#define WREG    (2 * IMGB)        // 9216 B per wave (A + B images)

typedef float    vf4  __attribute__((ext_vector_type(4)));
typedef _Float16 h8   __attribute__((ext_vector_type(8)));
typedef float    f16v __attribute__((ext_vector_type(16)));

#define G1 0.13533528f        // exp(-2)
#define G2 3.3546263e-4f      // exp(-8)
#define G3 1.5229979e-8f      // exp(-18)

// 7-bin window at rows i0..i0+6 via factored Gaussian (2 exp + 1 rcp):
//   w(t) = W0 * R^t * G(t), W0=exp(-968 v^2), R=exp(88 v), v = x - c_mid
__device__ __forceinline__ float window7(float x, int& i0, float* w)
{
    x = fminf(fmaxf(x, 0.0f), 1.0f);
    int ka = (int)floorf(fmaf(x, 22.0f, 0.5f));
    i0 = min(max(ka - 3, 0), 16);
    float v  = fmaf((float)(i0 + 3), -(1.0f / 22.0f), x);
    float W0 = __expf(-968.0f * v * v);
    float R  = __expf(88.0f * v);
    float Ri = __builtin_amdgcn_rcpf(R);
    float R2 = R * R,   R3 = R2 * R;
    float R2i = Ri * Ri, R3i = R2i * Ri;
    w[0] = W0 * (R3i * G3);
    w[1] = W0 * (R2i * G2);
    w[2] = W0 * (Ri  * G1);
    w[3] = W0;
    w[4] = W0 * (R   * G1);
    w[5] = W0 * (R2  * G2);
    w[6] = W0 * (R3  * G3);
    return ((w[0] + w[6]) + (w[1] + w[5])) + ((w[2] + w[4]) + w[3]);
}

// ---------------- K1: fused Parzen-window + MFMA joint histogram ----------------
__global__ __launch_bounds__(256)
void mi_mfma(const float* __restrict__ pred,
             const float* __restrict__ targ,
             float* __restrict__ partial)      // [NBATCH*PBLK][NCELLS]
{
    __shared__ __align__(16) char smem[4 * WREG];   // 36864 B -> 4 blocks/CU

    const int p    = blockIdx.x;
    const int b    = blockIdx.y;
    const int wv   = threadIdx.x >> 6;
    const int lane = threadIdx.x & 63;
    const int m    = lane & 31;               // bin row for fragment reads
    const int h    = lane >> 5;               // k-half selector

    char* wbase = smem + wv * WREG;
    _Float16* Aimg = (_Float16*)wbase;
    _Float16* Bimg = (_Float16*)(wbase + IMGB);

    const size_t base = (size_t)b * NVOX + (size_t)p * 2048 + (size_t)wv * 512
                      + (size_t)lane * 8;
    const vf4* __restrict__ px4 = (const vf4*)(pred + base);
    const vf4* __restrict__ py4 = (const vf4*)(targ + base);
    vf4 xa = px4[0], xb = px4[1], ya = py4[0], yb = py4[1];
    float xs[8] = {xa.x, xa.y, xa.z, xa.w, xb.x, xb.y, xb.z, xb.w};
    float ys[8] = {ya.x, ya.y, ya.z, ya.w, yb.x, yb.y, yb.z, yb.w};

    f16v acc = {};

    #pragma unroll
    for (int c = 0; c < 8; ++c) {
        // zero rows 0..23 of both images (3456 B each); rows 24..31 stay
        // garbage — they only pollute C rows/cols >= 23, which are never read
        vf4 z = {0.f, 0.f, 0.f, 0.f};
        #pragma unroll
        for (int it = 0; it < 3; ++it) {
            *(vf4*)(wbase        + (it * 64 + lane) * 16) = z;
            *(vf4*)(wbase + IMGB + (it * 64 + lane) * 16) = z;
        }
        if (lane < 24) {
            *(vf4*)(wbase        + (192 + lane) * 16) = z;
            *(vf4*)(wbase + IMGB + (192 + lane) * 16) = z;
        }

        int ia, ja;
        float wa[7], wb[7];
        float sa = window7(xs[c], ia, wa);
        float sb = window7(ys[c], ja, wb);
        float inv = __builtin_amdgcn_rcpf(sa * sb);   // fold both norms onto A

        #pragma unroll
        for (int t = 0; t < 7; ++t) {
            Aimg[(ia + t) * RS + lane] = (_Float16)(wa[t] * inv);  // RNE cvt
            Bimg[(ja + t) * RS + lane] = (_Float16)wb[t];
        }

        // 4 k-steps of 32x32x16 (K=16 voxels each)
        #pragma unroll
        for (int s = 0; s < 4; ++s) {
            h8 Af = *(const h8*)(Aimg + m * RS + 16 * s + 8 * h);
            h8 Bf = *(const h8*)(Bimg + m * RS + 16 * s + 8 * h);
            acc = __builtin_amdgcn_mfma_f32_32x32x16_f16(Af, Bf, acc, 0, 0, 0);
        }
    }

    // epilogue: C layout col=lane&31, row=(reg&3)+8*(reg>>2)+4*h (m74/m101)
    float* tile = (float*)wbase;               // reuse wave region
    #pragma unroll
    for (int r = 0; r < 16; ++r) {
        int row = (r & 3) + 8 * (r >> 2) + 4 * h;
        tile[row * 33 + m] = acc[r];
    }
    __syncthreads();
    for (int c = threadIdx.x; c < NCELLS; c += 256) {
        int i = c / NBINS, j = c % NBINS;
        float s = 0.0f;
        #pragma unroll
        for (int w = 0; w < 4; ++w)
            s += ((const float*)(smem + w * WREG))[i * 33 + j];
        partial[((size_t)(b * PBLK + p)) * NCELLS + c] = s;   // coalesced rows
    }
}

// ------ K2: per-batch coalesced fp64 reduction + marginals + MI (fused) ------
__global__ __launch_bounds__(256)
void mi_batch(const float* __restrict__ partial, float* __restrict__ out)
{
    const int b = blockIdx.x;
    const int t = threadIdx.x;
    const float* __restrict__ src = partial + (size_t)b * PBLK * NCELLS;

    // thread t owns cells t, t+256, t+512(<529); rows streamed coalesced
    double a0 = 0.0, a1 = 0.0, a2 = 0.0;
    for (int p = 0; p < PBLK; ++p) {
        const float* __restrict__ row = src + (size_t)p * NCELLS;
        a0 += (double)row[t];
        a1 += (double)row[256 + t];
        if (t < NCELLS - 512) a2 += (double)row[512 + t];
    }

    __shared__ double s_pab[NCELLS];
    __shared__ double s_pa[NBINS];
    __shared__ double s_pb[NBINS];
    __shared__ double s_red[4];

    const double invn = 1.0 / (double)NVOX;
    s_pab[t]       = a0 * invn;
    s_pab[256 + t] = a1 * invn;
    if (t < NCELLS - 512) s_pab[512 + t] = a2 * invn;
    __syncthreads();

    if (t < NBINS) {
        double r = 0.0, cl = 0.0;
        for (int j = 0; j < NBINS; ++j) {
            r  += s_pab[t * NBINS + j];
            cl += s_pab[j * NBINS + t];
        }
        s_pa[t] = r; s_pb[t] = cl;
    }
    __syncthreads();

    double s = 0.0;
    for (int c = t; c < NCELLS; c += 256) {
        double pv   = s_pab[c];
        double papb = s_pa[c / NBINS] * s_pb[c % NBINS];
        s += pv * log((pv + 1e-7) / (papb + 1e-7) + 1e-7);
    }
    #pragma unroll
    for (int off = 32; off > 0; off >>= 1) s += __shfl_down(s, off, 64);
    if ((t & 63) == 0) s_red[t >> 6] = s;
    __syncthreads();
    if (t == 0) {
        double mi = s_red[0] + s_red[1] + s_red[2] + s_red[3];
        atomicAdd(out, (float)(-mi * 0.25));
    }
}

extern "C" void kernel_launch(void* const* d_in, const int* in_sizes, int n_in,
                              void* d_out, int out_size, void* d_ws, size_t ws_size,
                              hipStream_t stream)
{
    const float* pred = (const float*)d_in[0];
    const float* targ = (const float*)d_in[1];
    float* out = (float*)d_out;
    float* partial = (float*)d_ws;   // NBATCH*PBLK*NCELLS f32 = 3.66 MB

    (void)hipMemsetAsync(d_out, 0, sizeof(float), stream);  // out is 0xAA-poisoned
    mi_mfma <<<dim3(PBLK, NBATCH), 256, 0, stream>>>(pred, targ, partial);
    mi_batch<<<NBATCH, 256, 0, stream>>>(partial, out);
}

// Round 8
// 107.847 us; speedup vs baseline: 1.9971x; 1.9971x over previous
//
#include <hip/hip_runtime.h>
#include <math.h>

// MutualInformationLoss on MI355X — round 8.
// Round-7 lesson: fusing reduce+final into 4 blocks made the reduction
// latency-bound (123 us: 432-deep dependent-load chain at cross-XCD L2
// latency, occupancy 0.18%). Reduction needs coalescing AND parallelism:
//   K2 mi_reduce: grid 27x4, each block streams 16 partial rows coalesced,
//                 fp64 register accumulate, <=3 fp64 atomicAdds -> pab64.
//   K3 mi_final : 1 block, marginals + MI in fp64, writes out[0] directly.
// K1 unchanged (~43 us, LDS-pipe-bound). Harness ws-poison fill (~44 us) is
// a fixed floor inside the timed replay.

#define NBINS   23
#define NCELLS  529
#define NBATCH  4
#define NVOX    884736
#define PBLK    432               // K1 blocks per batch: 432 * 2048 = 884736
#define RPB     16                // partial rows per mi_reduce block (432/27)
#define RBLK    (PBLK / RPB)      // 27
#define RS      72                // image row stride in halves (144 B)
#define IMGB    (32 * RS * 2)     // 4608 B per image (32 rows)
#define WREG    (2 * IMGB)        // 9216 B per wave (A + B images)

typedef float    vf4  __attribute__((ext_vector_type(4)));
typedef _Float16 h8   __attribute__((ext_vector_type(8)));
typedef float    f16v __attribute__((ext_vector_type(16)));

#define G1 0.13533528f        // exp(-2)
#define G2 3.3546263e-4f      // exp(-8)
#define G3 1.5229979e-8f      // exp(-18)

// 7-bin window at rows i0..i0+6 via factored Gaussian (2 exp + 1 rcp):
//   w(t) = W0 * R^t * G(t), W0=exp(-968 v^2), R=exp(88 v), v = x - c_mid
__device__ __forceinline__ float window7(float x, int& i0, float* w)
{
    x = fminf(fmaxf(x, 0.0f), 1.0f);
    int ka = (int)floorf(fmaf(x, 22.0f, 0.5f));
    i0 = min(max(ka - 3, 0), 16);
    float v  = fmaf((float)(i0 + 3), -(1.0f / 22.0f), x);
    float W0 = __expf(-968.0f * v * v);
    float R  = __expf(88.0f * v);
    float Ri = __builtin_amdgcn_rcpf(R);
    float R2 = R * R,   R3 = R2 * R;
    float R2i = Ri * Ri, R3i = R2i * Ri;
    w[0] = W0 * (R3i * G3);
    w[1] = W0 * (R2i * G2);
    w[2] = W0 * (Ri  * G1);
    w[3] = W0;
    w[4] = W0 * (R   * G1);
    w[5] = W0 * (R2  * G2);
    w[6] = W0 * (R3  * G3);
    return ((w[0] + w[6]) + (w[1] + w[5])) + ((w[2] + w[4]) + w[3]);
}

// ---------------- K1: fused Parzen-window + MFMA joint histogram ----------------
__global__ __launch_bounds__(256)
void mi_mfma(const float* __restrict__ pred,
             const float* __restrict__ targ,
             float* __restrict__ partial)      // [NBATCH*PBLK][NCELLS]
{
    __shared__ __align__(16) char smem[4 * WREG];   // 36864 B -> 4 blocks/CU

    const int p    = blockIdx.x;
    const int b    = blockIdx.y;
    const int wv   = threadIdx.x >> 6;
    const int lane = threadIdx.x & 63;
    const int m    = lane & 31;               // bin row for fragment reads
    const int h    = lane >> 5;               // k-half selector

    char* wbase = smem + wv * WREG;
    _Float16* Aimg = (_Float16*)wbase;
    _Float16* Bimg = (_Float16*)(wbase + IMGB);

    const size_t base = (size_t)b * NVOX + (size_t)p * 2048 + (size_t)wv * 512
                      + (size_t)lane * 8;
    const vf4* __restrict__ px4 = (const vf4*)(pred + base);
    const vf4* __restrict__ py4 = (const vf4*)(targ + base);
    vf4 xa = px4[0], xb = px4[1], ya = py4[0], yb = py4[1];
    float xs[8] = {xa.x, xa.y, xa.z, xa.w, xb.x, xb.y, xb.z, xb.w};
    float ys[8] = {ya.x, ya.y, ya.z, ya.w, yb.x, yb.y, yb.z, yb.w};

    f16v acc = {};

    #pragma unroll
    for (int c = 0; c < 8; ++c) {
        // zero rows 0..23 of both images (3456 B each); rows 24..31 stay
        // garbage — they only pollute C rows/cols >= 23, which are never read
        vf4 z = {0.f, 0.f, 0.f, 0.f};
        #pragma unroll
        for (int it = 0; it < 3; ++it) {
            *(vf4*)(wbase        + (it * 64 + lane) * 16) = z;
            *(vf4*)(wbase + IMGB + (it * 64 + lane) * 16) = z;
        }
        if (lane < 24) {
            *(vf4*)(wbase        + (192 + lane) * 16) = z;
            *(vf4*)(wbase + IMGB + (192 + lane) * 16) = z;
        }

        int ia, ja;
        float wa[7], wb[7];
        float sa = window7(xs[c], ia, wa);
        float sb = window7(ys[c], ja, wb);
        float inv = __builtin_amdgcn_rcpf(sa * sb);   // fold both norms onto A

        #pragma unroll
        for (int t = 0; t < 7; ++t) {
            Aimg[(ia + t) * RS + lane] = (_Float16)(wa[t] * inv);  // RNE cvt
            Bimg[(ja + t) * RS + lane] = (_Float16)wb[t];
        }

        // 4 k-steps of 32x32x16 (K=16 voxels each)
        #pragma unroll
        for (int s = 0; s < 4; ++s) {
            h8 Af = *(const h8*)(Aimg + m * RS + 16 * s + 8 * h);
            h8 Bf = *(const h8*)(Bimg + m * RS + 16 * s + 8 * h);
            acc = __builtin_amdgcn_mfma_f32_32x32x16_f16(Af, Bf, acc, 0, 0, 0);
        }
    }

    // epilogue: C layout col=lane&31, row=(reg&3)+8*(reg>>2)+4*h (m74/m101)
    float* tile = (float*)wbase;               // reuse wave region
    #pragma unroll
    for (int r = 0; r < 16; ++r) {
        int row = (r & 3) + 8 * (r >> 2) + 4 * h;
        tile[row * 33 + m] = acc[r];
    }
    __syncthreads();
    for (int c = threadIdx.x; c < NCELLS; c += 256) {
        int i = c / NBINS, j = c % NBINS;
        float s = 0.0f;
        #pragma unroll
        for (int w = 0; w < 4; ++w)
            s += ((const float*)(smem + w * WREG))[i * 33 + j];
        partial[((size_t)(b * PBLK + p)) * NCELLS + c] = s;   // coalesced rows
    }
}

// ------ K2: coalesced + parallel fp64 reduction (27 blocks per batch) ------
__global__ __launch_bounds__(256)
void mi_reduce(const float* __restrict__ partial, double* __restrict__ pab64)
{
    const int g = blockIdx.x;                 // 0..RBLK-1
    const int b = blockIdx.y;
    const int t = threadIdx.x;
    const float* __restrict__ src =
        partial + ((size_t)b * PBLK + (size_t)g * RPB) * NCELLS;

    double a0 = 0.0, a1 = 0.0, a2 = 0.0;
    #pragma unroll
    for (int p = 0; p < RPB; ++p) {
        const float* __restrict__ row = src + (size_t)p * NCELLS;
        a0 += (double)row[t];
        a1 += (double)row[256 + t];
        if (t < NCELLS - 512) a2 += (double)row[512 + t];
    }
    atomicAdd(&pab64[b * NCELLS + t],       a0);
    atomicAdd(&pab64[b * NCELLS + 256 + t], a1);
    if (t < NCELLS - 512) atomicAdd(&pab64[b * NCELLS + 512 + t], a2);
}

// ---------------- K3: fp64 marginals + MI ----------------
__global__ __launch_bounds__(256)
void mi_final(const double* __restrict__ pab64, float* __restrict__ out)
{
    __shared__ double s_pab[NCELLS];
    __shared__ double s_pa[NBINS];
    __shared__ double s_pb[NBINS];
    __shared__ double s_red[4];

    double total = 0.0;
    for (int b = 0; b < NBATCH; ++b) {
        for (int c = threadIdx.x; c < NCELLS; c += 256)
            s_pab[c] = pab64[b * NCELLS + c] * (1.0 / (double)NVOX);
        __syncthreads();
        if (threadIdx.x < NBINS) {
            const int i = threadIdx.x;
            double r = 0.0, cl = 0.0;
            for (int j = 0; j < NBINS; ++j) {
                r  += s_pab[i * NBINS + j];
                cl += s_pab[j * NBINS + i];
            }
            s_pa[i] = r; s_pb[i] = cl;
        }
        __syncthreads();
        double t = 0.0;
        for (int c = threadIdx.x; c < NCELLS; c += 256) {
            double pv   = s_pab[c];
            double papb = s_pa[c / NBINS] * s_pb[c % NBINS];
            t += pv * log((pv + 1e-7) / (papb + 1e-7) + 1e-7);
        }
        #pragma unroll
        for (int off = 32; off > 0; off >>= 1) t += __shfl_down(t, off, 64);
        if ((threadIdx.x & 63) == 0) s_red[threadIdx.x >> 6] = t;
        __syncthreads();
        if (threadIdx.x == 0) total += s_red[0] + s_red[1] + s_red[2] + s_red[3];
        __syncthreads();
    }
    if (threadIdx.x == 0) out[0] = (float)(-total * 0.25);
}

extern "C" void kernel_launch(void* const* d_in, const int* in_sizes, int n_in,
                              void* d_out, int out_size, void* d_ws, size_t ws_size,
                              hipStream_t stream)
{
    const float* pred = (const float*)d_in[0];
    const float* targ = (const float*)d_in[1];
    float* out = (float*)d_out;
    char* ws = (char*)d_ws;

    // layout: [partial: NBATCH*PBLK*NCELLS f32 = 3.66 MB][pab64: 2116 f64]
    const size_t off_partial = 0;
    const size_t off_pab64   =
        ((size_t)NBATCH * PBLK * NCELLS * 4 + 255) & ~(size_t)255;

    float*  partial = (float*)(ws + off_partial);
    double* pab64   = (double*)(ws + off_pab64);

    (void)hipMemsetAsync(pab64, 0, (size_t)NBATCH * NCELLS * sizeof(double), stream);
    mi_mfma  <<<dim3(PBLK, NBATCH), 256, 0, stream>>>(pred, targ, partial);
    mi_reduce<<<dim3(RBLK, NBATCH), 256, 0, stream>>>(partial, pab64);
    mi_final <<<1, 256, 0, stream>>>(pab64, out);
}